// Round 9
// baseline (123.327 us; speedup 1.0000x reference)
//
#include <hip/hip_runtime.h>
#include <hip/hip_fp16.h>

// VectorBasis R21. Base = R19 (118.3us best; R20's SoA split regressed +3.8:
// 3-4 narrow load streams lost to one dwordx4 -- gather is instruction/
// latency-limited, not byte-limited). Two changes:
//  1) phase2 SUPERBIN-256: phase1 chunks are bin-sorted, so bins 2s,2s+1 are
//     ADJACENT runs -> a block owning 256 atoms reads ONE contiguous ~168B
//     run per source block (was 2x 84B). Line waste 1.6x->~1.35x, table work
//     per record halves, 391 blocks @ 3/CU all resident, single window
//     (CAPR=8192 = mean+64sigma). atom = c&255 since superbin = c>>8.
//  2) phase1 __frsqrt_rn: one v_rsq_f32 replaces precise sqrt+div; few-ulp
//     error << fp16 record noise; d~5.0 fuzz lands where taper~0.
// Frozen, proven: int fixed-point LDS accumulate (R15/R17: f32 LDS atomics
// ~200cyc CAS), T1 XCD swizzle (R18 -3.5us), abase window table + PH1_REC=
// 4096 fragmentation halving (R19 -4.6us), AoS int4 payload + one-dwordx4
// gather (R20 lesson), block-major coalesced dump (R14), no records in regs
// across barriers (R16 spill). ~90us harness ws-poison fills bound the wall.

constexpr int NSP  = 4;
constexpr int NRAD = 8;
constexpr int NPS  = 4;
constexpr int DDIM = NRAD * NPS;       // 32

constexpr int APB       = 128;         // atoms per phase1 bin
constexpr int APB_SH    = 7;
constexpr int APB2      = 256;         // atoms per phase2 superbin
constexpr int NBIN_PAD  = 832;         // 64*13 >= nbin(782)
constexpr int NROWS_PAD = 448;         // 64*7 > nblocks(391) (scan sentinel)
constexpr int RS        = 840;         // runoff row stride (u16), >= nbin+1
constexpr int PH1_BLK   = 1024;
constexpr int PH1_U     = 4;
constexpr int PH1_REC   = PH1_BLK * PH1_U;  // 4096
constexpr int CAPR      = 8192;        // phase2 window (records)
constexpr int P2_BLK    = 512;
constexpr int NXCD      = 8;

constexpr float ACC_SCALE     = 32768.0f;        // 2^15 fixed point
constexpr float ACC_INV_SCALE = 1.0f / 32768.0f;

__device__ __forceinline__ unsigned pack2(float a, float b) {
    union { __half2 h; unsigned u; } cv;
    cv.h = __floats2half2_rn(a, b);
    return cv.u;
}
__device__ __forceinline__ float2 unpack2(unsigned u) {
    union { unsigned u; __half2 h; } cv;
    cv.u = u;
    return __half22float2(cv.h);
}

__device__ __forceinline__ void build_w2(
    float* sW2, const float* cemb, const float* Wc, const float* W_alch,
    int tid, int nthreads)
{
    for (int i = tid; i < 3 * NRAD * 16; i += nthreads) {
        int p  = i & 15;
        int n  = (i >> 4) & 7;
        int o  = i >> 7;
        int sc = p >> 2, sn = p & 3;
        float w = 0.0f;
        #pragma unroll
        for (int q = 0; q < NPS; q++)
            w += cemb[sc * DDIM + n * NPS + q] * Wc[o * DDIM + n * NPS + q]
               * W_alch[sn * NPS + q];
        sW2[i] = w;
    }
}

__device__ __forceinline__ bool edge_math(
    float vx, float vy, float vz, int pair, const float* sW2,
    float g[3], float t[3])
{
    float d2    = vx * vx + vy * vy + vz * vz + 1e-12f;
    float inv_d = __frsqrt_rn(d2);     // v_rsq_f32
    float d     = d2 * inv_d;

    const float PI = 3.14159265358979323846f;
    const float RCUT = 5.0f, INNER = 4.5f, INVW = 2.0f;
    if (d >= RCUT) return false;
    float taper = 0.5f * (__cosf(PI * (d - INNER) * INVW) + 1.0f);
    float fc = (d < INNER) ? 1.0f : taper;

    float theta = (PI / RCUT) * d;
    float s1 = __sinf(theta);
    float c1 = __cosf(theta);
    float two_c = 2.0f * c1;
    float R[NRAD];
    R[0] = s1 * inv_d;
    float sm2 = 0.0f, sm1 = s1;
    #pragma unroll
    for (int n = 1; n < NRAD; n++) {
        float s = two_c * sm1 - sm2;
        sm2 = sm1; sm1 = s;
        R[n] = s * inv_d;
    }

    #pragma unroll
    for (int o = 0; o < 3; o++) {
        float acc = 0.0f;
        #pragma unroll
        for (int n = 0; n < NRAD; n++)
            acc += R[n] * sW2[(o * NRAD + n) * 16 + pair];
        t[o] = acc;
    }
    g[0] = fc * vy * inv_d;
    g[1] = fc * vz * inv_d;
    g[2] = fc * vx * inv_d;
    return true;
}

// ====== phase1: block-private sorted chunk + offset table ===================
__global__ __launch_bounds__(PH1_BLK) void vb_phase1(
    const float* __restrict__ vecs,
    const int*   __restrict__ centers,
    const int*   __restrict__ neighbors,
    const int*   __restrict__ species,
    const float* __restrict__ W_alch,
    const float* __restrict__ cemb,
    const float* __restrict__ Wc,
    unsigned short* __restrict__ runoff,  // (nblocks, RS)
    int4*        __restrict__ payload,    // (nblocks, PH1_REC)
    int E, int nbin)
{
    __shared__ float sW2[3 * NRAD * 16];        // 1.5 KB
    __shared__ int4  srec[PH1_REC];             // 64 KB
    __shared__ unsigned lcntP[NBIN_PAD / 2];    // 1.66 KB packed u16 pairs
    __shared__ unsigned short lexcl[NBIN_PAD];  // 1.66 KB
    __shared__ int sTotal;                      // ~70 KB -> 2 blocks/CU

    int tid = threadIdx.x;
    build_w2(sW2, cemb, Wc, W_alch, tid, PH1_BLK);
    for (int i = tid; i < NBIN_PAD / 2; i += PH1_BLK) lcntP[i] = 0;
    __syncthreads();

    int4 rec[PH1_U];
    int  rnk[PH1_U];   // static indices only — stays in VGPRs
    #pragma unroll
    for (int u = 0; u < PH1_U; u++) {
        int e = blockIdx.x * PH1_REC + u * PH1_BLK + tid;
        rec[u].x = -1;
        rnk[u]   = 0;
        if (e < E) {
            float vx = vecs[3 * e + 0];
            float vy = vecs[3 * e + 1];
            float vz = vecs[3 * e + 2];
            int c  = centers[e];
            int pair = species[c] * 4 + species[neighbors[e]];
            float g[3], t[3];
            if (edge_math(vx, vy, vz, pair, sW2, g, t)) {
                rec[u].x = c;
                rec[u].y = (int)pack2(g[0], g[1]);
                rec[u].z = (int)pack2(g[2], t[0]);
                rec[u].w = (int)pack2(t[1], t[2]);
                int bin = c >> APB_SH;
                int sh  = (bin & 1) << 4;
                unsigned old = atomicAdd(&lcntP[bin >> 1], 1u << sh);
                rnk[u] = (int)((old >> sh) & 0xffff);   // arrival rank in bin
            }
        }
    }
    __syncthreads();

    // single-wave exclusive scan over NBIN_PAD bins (13/lane), packed counts
    if (tid < 64) {
        int base = tid * 13;
        int pre[13];
        int sum = 0;
        #pragma unroll
        for (int j = 0; j < 13; j++) {
            int b = base + j;
            int n = (lcntP[b >> 1] >> ((b & 1) << 4)) & 0xffff;
            pre[j] = sum; sum += n;
        }
        int incl = sum;
        #pragma unroll
        for (int off = 1; off < 64; off <<= 1) {
            int t = __shfl_up(incl, off, 64);
            if (tid >= off) incl += t;
        }
        int ex = incl - sum;
        #pragma unroll
        for (int j = 0; j < 13; j++)
            lexcl[base + j] = (unsigned short)(ex + pre[j]);
        if (tid == 63) sTotal = incl;
    }
    __syncthreads();

    // scatter records into LDS sorted by bin — NO atomic (slot = excl + rank)
    #pragma unroll
    for (int u = 0; u < PH1_U; u++) {
        if (rec[u].x >= 0) {
            int bin = rec[u].x >> APB_SH;
            srec[(int)lexcl[bin] + rnk[u]] = rec[u];
        }
    }
    __syncthreads();

    // fully coalesced chunk dump + offset table
    int total = sTotal;
    size_t pbase = (size_t)blockIdx.x * PH1_REC;
    for (int i = tid; i < total; i += PH1_BLK)
        payload[pbase + i] = srec[i];
    unsigned short* ro = runoff + (size_t)blockIdx.x * RS;
    for (int b = tid; b <= nbin; b += PH1_BLK)
        ro[b] = (b < nbin) ? lexcl[b] : (unsigned short)total;
}

// ====== phase2: superbin-256 abase gather -> int LDS atomics -> writeout ====
__global__ __launch_bounds__(P2_BLK) void vb_phase2(
    const unsigned short* __restrict__ runoff,   // (nblocks, RS)
    const int4*           __restrict__ payload,  // (nblocks, PH1_REC)
    float*                __restrict__ out,      // (A,9), fully overwritten
    int A, int nblocks, int nbin)
{
    __shared__ unsigned short sst[NROWS_PAD];   // 0.9 KB run start in block
    __shared__ unsigned short roff[NROWS_PAD];  // 0.9 KB excl scan of lens
    __shared__ int   abase[CAPR];               // 32 KB addr base per position
    __shared__ int   sacc[APB2 * 9];            // 9 KB fixed-point acc
    __shared__ int sTotal;                      // ~43.8 KB -> 3 blocks/CU

    // XCD-affinity superbin swizzle (T1, bijective): group ~nsb/8 CONSECUTIVE
    // superbins per XCD so payload lines shared by adjacent superbins' runs
    // are fetched into ONE per-XCD L2.  (R18: -3.5us)
    int nsb = gridDim.x;
    int q = nsb / NXCD, r0 = nsb % NXCD;
    int xcd = blockIdx.x % NXCD, loc = blockIdx.x / NXCD;
    int sb = (xcd < r0 ? xcd * (q + 1) : r0 * (q + 1) + (xcd - r0) * q) + loc;

    int tid = threadIdx.x;

    // run table: superbin sb = phase1 bins (2sb, 2sb+1), which are ADJACENT
    // runs in every bin-sorted chunk -> one contiguous segment per block.
    int c0 = 2 * sb;
    int c2 = min(c0 + 2, nbin);
    for (int r = tid; r < NROWS_PAD; r += P2_BLK) {
        unsigned short s0 = 0, len = 0;
        if (r < nblocks) {
            const unsigned short* row = runoff + (size_t)r * RS;
            unsigned short a = row[c0];
            unsigned short c = row[c2];
            s0  = a;
            len = (unsigned short)(c - a);
        }
        sst[r]  = s0;
        roff[r] = len;   // temporarily lengths; scanned in place below
    }
    for (int i = tid; i < APB2 * 9; i += P2_BLK) sacc[i] = 0;
    __syncthreads();

    // single-wave exclusive scan over NROWS_PAD rows (7/lane).
    // rows >= nblocks have len 0 so roff[nblocks] == total (sentinel,
    // in-range since nblocks < NROWS_PAD).
    if (tid < 64) {
        int base = tid * 7;
        int pre[7];
        int sum = 0;
        #pragma unroll
        for (int j = 0; j < 7; j++) { pre[j] = sum; sum += roff[base + j]; }
        int incl = sum;
        #pragma unroll
        for (int off = 1; off < 64; off <<= 1) {
            int t = __shfl_up(incl, off, 64);
            if (tid >= off) incl += t;
        }
        int ex = incl - sum;
        #pragma unroll
        for (int j = 0; j < 7; j++)
            roff[base + j] = (unsigned short)(ex + pre[j]);
        if (tid == 63) sTotal = incl;
    }
    __syncthreads();

    int total = sTotal;

    for (int w0 = 0; w0 < total; w0 += CAPR) {       // virtually always 1 pass
        int wend = min(w0 + CAPR, total);
        int nc = wend - w0;

        // abase for this window: disjoint clipped row ranges, no atomics.
        // abase[p-w0] = r*PH1_REC + sst[r] - roff[r]  =>  payload index of
        // global position p is simply p + abase[p-w0].
        for (int r = tid; r < nblocks; r += P2_BLK) {
            int s  = max((int)roff[r], w0);
            int e2 = min((int)roff[r + 1], wend);
            int base_r = r * PH1_REC + (int)sst[r] - (int)roff[r];
            for (int p = s; p < e2; p++)
                abase[p - w0] = base_r;
        }
        __syncthreads();

        // stream records (one dwordx4 each), accumulate via int LDS atomics
        for (int i = tid; i < nc; i += P2_BLK) {
            int4 r = payload[(size_t)(w0 + i + abase[i])];
            int atom = r.x & (APB2 - 1);     // atom-in-superbin (c & 255)
            float2 g01 = unpack2((unsigned)r.y);
            float2 g2t = unpack2((unsigned)r.z);
            float2 t12 = unpack2((unsigned)r.w);
            float g0 = g01.x * ACC_SCALE, g1 = g01.y * ACC_SCALE;
            float g2 = g2t.x * ACC_SCALE;
            float t0 = g2t.y, t1 = t12.x, t2 = t12.y;
            int* s = &sacc[atom * 9];
            atomicAdd(s + 0, __float2int_rn(g0 * t0));
            atomicAdd(s + 1, __float2int_rn(g0 * t1));
            atomicAdd(s + 2, __float2int_rn(g0 * t2));
            atomicAdd(s + 3, __float2int_rn(g1 * t0));
            atomicAdd(s + 4, __float2int_rn(g1 * t1));
            atomicAdd(s + 5, __float2int_rn(g1 * t2));
            atomicAdd(s + 6, __float2int_rn(g2 * t0));
            atomicAdd(s + 7, __float2int_rn(g2 * t1));
            atomicAdd(s + 8, __float2int_rn(g2 * t2));
        }
        __syncthreads();   // abase reused next window (rare)
    }

    // scaled overwrite of out (coalesced)
    size_t gbase = (size_t)sb * APB2 * 9;
    size_t lim = (size_t)A * 9;
    for (int i = tid; i < APB2 * 9; i += P2_BLK) {
        size_t gi = gbase + i;
        if (gi < lim) out[gi] = (float)sacc[i] * ACC_INV_SCALE;
    }
}

// Fallback: direct per-edge global atomics (correct, slow).
__global__ __launch_bounds__(256) void vb_edge_fallback(
    const float* __restrict__ vecs,
    const int*   __restrict__ centers,
    const int*   __restrict__ neighbors,
    const int*   __restrict__ species,
    const float* __restrict__ W_alch,
    const float* __restrict__ cemb,
    const float* __restrict__ Wc,
    float*       __restrict__ out,
    int E)
{
    __shared__ float sW2[3 * NRAD * 16];
    build_w2(sW2, cemb, Wc, W_alch, threadIdx.x, blockDim.x);
    __syncthreads();

    int e = blockIdx.x * blockDim.x + threadIdx.x;
    if (e >= E) return;
    float vx = vecs[3 * e + 0], vy = vecs[3 * e + 1], vz = vecs[3 * e + 2];
    int c = centers[e];
    int pair = species[c] * 4 + species[neighbors[e]];
    float g[3], t[3];
    if (!edge_math(vx, vy, vz, pair, sW2, g, t)) return;
    float* op = out + (size_t)c * 9;
    #pragma unroll
    for (int m = 0; m < 3; m++)
        #pragma unroll
        for (int o = 0; o < 3; o++)
            atomicAdd(op + m * 3 + o, g[m] * t[o]);
}

extern "C" void kernel_launch(void* const* d_in, const int* in_sizes, int n_in,
                              void* d_out, int out_size, void* d_ws, size_t ws_size,
                              hipStream_t stream) {
    const float* vecs      = (const float*)d_in[0];
    const int*   centers   = (const int*)d_in[1];
    const int*   neighbors = (const int*)d_in[2];
    const int*   species   = (const int*)d_in[3];
    const float* W_alch    = (const float*)d_in[6];
    const float* cemb      = (const float*)d_in[7];
    const float* Wc        = (const float*)d_in[8];
    float*       out       = (float*)d_out;

    int E = in_sizes[1];
    int A = in_sizes[3];
    int nbin    = (A + APB - 1) >> APB_SH;
    int nsb     = (A + APB2 - 1) / APB2;
    int nblocks = (E + PH1_REC - 1) / PH1_REC;

    // ws: [runoff nblocks*RS u16][payload nblocks*4096*16B]
    size_t ro_bytes = ((size_t)nblocks * RS * 2 + 255) & ~(size_t)255;
    size_t need = ro_bytes + (size_t)nblocks * PH1_REC * 16;

    if (nbin + 1 <= RS && nbin <= NBIN_PAD && nblocks < NROWS_PAD &&
        need <= ws_size) {
        unsigned short* runoff = (unsigned short*)d_ws;
        int4* payload = (int4*)((char*)d_ws + ro_bytes);

        vb_phase1<<<nblocks, PH1_BLK, 0, stream>>>(vecs, centers, neighbors,
                                                   species, W_alch, cemb, Wc,
                                                   runoff, payload, E, nbin);
        vb_phase2<<<nsb, P2_BLK, 0, stream>>>(runoff, payload, out, A,
                                              nblocks, nbin);
    } else {
        hipMemsetAsync(d_out, 0, (size_t)out_size * sizeof(float), stream);
        int grid = (E + 255) / 256;
        vb_edge_fallback<<<grid, 256, 0, stream>>>(vecs, centers, neighbors,
                                                   species, W_alch, cemb, Wc,
                                                   out, E);
    }
}

// Round 10
// 117.649 us; speedup vs baseline: 1.0483x; 1.0483x over previous
//
#include <hip/hip_runtime.h>
#include <hip/hip_fp16.h>

// VectorBasis R22 = R19 (118.3us, best) + ONE isolated change: __frsqrt_rn
// in edge_math (v_rsq_f32 replaces precise sqrtf+div; ~10 VALU/edge saved;
// few-ulp error << fp16 record quantization; d~5.0 fuzz lands where
// taper~0). R20 (SoA planes, +3.8) and R21 (superbin-256, +5.0) both
// REGRESSED and are reverted: phase2's R19 configuration is a local optimum
// -- 84B runs already amortize line waste, 4 blocks/CU x 512 = full 32
// waves/CU, and further byte/table savings lose to occupancy or stream
// count. Frozen, proven: int fixed-point LDS accumulate (R15/R17: f32 LDS
// atomics ~200cyc CAS), T1 XCD bin swizzle (R18 -3.5us), abase window table
// + PH1_REC=4096 fragmentation halving (R19 -4.6us), AoS int4 payload +
// one-dwordx4 gather (R20 lesson), block-major coalesced dump (R14), no
// records in regs across barriers (R16 spill lesson).
// ~90us of harness ws-poison fills bounds the wall from below.

constexpr int NSP  = 4;
constexpr int NRAD = 8;
constexpr int NPS  = 4;
constexpr int DDIM = NRAD * NPS;       // 32

constexpr int APB       = 128;         // atoms per bin
constexpr int APB_SH    = 7;
constexpr int NBIN_PAD  = 832;         // 64*13 >= nbin(782)
constexpr int NROWS_PAD = 448;         // 64*7 > nblocks(391) (scan sentinel)
constexpr int RS        = 840;         // runoff row stride (u16), >= nbin+1
constexpr int PH1_BLK   = 1024;
constexpr int PH1_U     = 4;
constexpr int PH1_REC   = PH1_BLK * PH1_U;  // 4096
constexpr int CAPR      = 4096;        // phase2 window (records)
constexpr int P2_BLK    = 512;
constexpr int NXCD      = 8;

constexpr float ACC_SCALE     = 32768.0f;        // 2^15 fixed point
constexpr float ACC_INV_SCALE = 1.0f / 32768.0f;

__device__ __forceinline__ unsigned pack2(float a, float b) {
    union { __half2 h; unsigned u; } cv;
    cv.h = __floats2half2_rn(a, b);
    return cv.u;
}
__device__ __forceinline__ float2 unpack2(unsigned u) {
    union { unsigned u; __half2 h; } cv;
    cv.u = u;
    return __half22float2(cv.h);
}

__device__ __forceinline__ void build_w2(
    float* sW2, const float* cemb, const float* Wc, const float* W_alch,
    int tid, int nthreads)
{
    for (int i = tid; i < 3 * NRAD * 16; i += nthreads) {
        int p  = i & 15;
        int n  = (i >> 4) & 7;
        int o  = i >> 7;
        int sc = p >> 2, sn = p & 3;
        float w = 0.0f;
        #pragma unroll
        for (int q = 0; q < NPS; q++)
            w += cemb[sc * DDIM + n * NPS + q] * Wc[o * DDIM + n * NPS + q]
               * W_alch[sn * NPS + q];
        sW2[i] = w;
    }
}

__device__ __forceinline__ bool edge_math(
    float vx, float vy, float vz, int pair, const float* sW2,
    float g[3], float t[3])
{
    float d2    = vx * vx + vy * vy + vz * vz + 1e-12f;
    float inv_d = __frsqrt_rn(d2);     // v_rsq_f32
    float d     = d2 * inv_d;

    const float PI = 3.14159265358979323846f;
    const float RCUT = 5.0f, INNER = 4.5f, INVW = 2.0f;
    if (d >= RCUT) return false;
    float taper = 0.5f * (__cosf(PI * (d - INNER) * INVW) + 1.0f);
    float fc = (d < INNER) ? 1.0f : taper;

    float theta = (PI / RCUT) * d;
    float s1 = __sinf(theta);
    float c1 = __cosf(theta);
    float two_c = 2.0f * c1;
    float R[NRAD];
    R[0] = s1 * inv_d;
    float sm2 = 0.0f, sm1 = s1;
    #pragma unroll
    for (int n = 1; n < NRAD; n++) {
        float s = two_c * sm1 - sm2;
        sm2 = sm1; sm1 = s;
        R[n] = s * inv_d;
    }

    #pragma unroll
    for (int o = 0; o < 3; o++) {
        float acc = 0.0f;
        #pragma unroll
        for (int n = 0; n < NRAD; n++)
            acc += R[n] * sW2[(o * NRAD + n) * 16 + pair];
        t[o] = acc;
    }
    g[0] = fc * vy * inv_d;
    g[1] = fc * vz * inv_d;
    g[2] = fc * vx * inv_d;
    return true;
}

// ====== phase1: block-private sorted chunk + offset table ===================
__global__ __launch_bounds__(PH1_BLK) void vb_phase1(
    const float* __restrict__ vecs,
    const int*   __restrict__ centers,
    const int*   __restrict__ neighbors,
    const int*   __restrict__ species,
    const float* __restrict__ W_alch,
    const float* __restrict__ cemb,
    const float* __restrict__ Wc,
    unsigned short* __restrict__ runoff,  // (nblocks, RS)
    int4*        __restrict__ payload,    // (nblocks, PH1_REC)
    int E, int nbin)
{
    __shared__ float sW2[3 * NRAD * 16];        // 1.5 KB
    __shared__ int4  srec[PH1_REC];             // 64 KB
    __shared__ unsigned lcntP[NBIN_PAD / 2];    // 1.66 KB packed u16 pairs
    __shared__ unsigned short lexcl[NBIN_PAD];  // 1.66 KB
    __shared__ int sTotal;                      // ~70 KB -> 2 blocks/CU

    int tid = threadIdx.x;
    build_w2(sW2, cemb, Wc, W_alch, tid, PH1_BLK);
    for (int i = tid; i < NBIN_PAD / 2; i += PH1_BLK) lcntP[i] = 0;
    __syncthreads();

    int4 rec[PH1_U];
    int  rnk[PH1_U];   // static indices only — stays in VGPRs
    #pragma unroll
    for (int u = 0; u < PH1_U; u++) {
        int e = blockIdx.x * PH1_REC + u * PH1_BLK + tid;
        rec[u].x = -1;
        rnk[u]   = 0;
        if (e < E) {
            float vx = vecs[3 * e + 0];
            float vy = vecs[3 * e + 1];
            float vz = vecs[3 * e + 2];
            int c  = centers[e];
            int pair = species[c] * 4 + species[neighbors[e]];
            float g[3], t[3];
            if (edge_math(vx, vy, vz, pair, sW2, g, t)) {
                rec[u].x = c;
                rec[u].y = (int)pack2(g[0], g[1]);
                rec[u].z = (int)pack2(g[2], t[0]);
                rec[u].w = (int)pack2(t[1], t[2]);
                int bin = c >> APB_SH;
                int sh  = (bin & 1) << 4;
                unsigned old = atomicAdd(&lcntP[bin >> 1], 1u << sh);
                rnk[u] = (int)((old >> sh) & 0xffff);   // arrival rank in bin
            }
        }
    }
    __syncthreads();

    // single-wave exclusive scan over NBIN_PAD bins (13/lane), packed counts
    if (tid < 64) {
        int base = tid * 13;
        int pre[13];
        int sum = 0;
        #pragma unroll
        for (int j = 0; j < 13; j++) {
            int b = base + j;
            int n = (lcntP[b >> 1] >> ((b & 1) << 4)) & 0xffff;
            pre[j] = sum; sum += n;
        }
        int incl = sum;
        #pragma unroll
        for (int off = 1; off < 64; off <<= 1) {
            int t = __shfl_up(incl, off, 64);
            if (tid >= off) incl += t;
        }
        int ex = incl - sum;
        #pragma unroll
        for (int j = 0; j < 13; j++)
            lexcl[base + j] = (unsigned short)(ex + pre[j]);
        if (tid == 63) sTotal = incl;
    }
    __syncthreads();

    // scatter records into LDS sorted by bin — NO atomic (slot = excl + rank)
    #pragma unroll
    for (int u = 0; u < PH1_U; u++) {
        if (rec[u].x >= 0) {
            int bin = rec[u].x >> APB_SH;
            srec[(int)lexcl[bin] + rnk[u]] = rec[u];
        }
    }
    __syncthreads();

    // fully coalesced chunk dump + offset table
    int total = sTotal;
    size_t pbase = (size_t)blockIdx.x * PH1_REC;
    for (int i = tid; i < total; i += PH1_BLK)
        payload[pbase + i] = srec[i];
    unsigned short* ro = runoff + (size_t)blockIdx.x * RS;
    for (int b = tid; b <= nbin; b += PH1_BLK)
        ro[b] = (b < nbin) ? lexcl[b] : (unsigned short)total;
}

// ====== phase2: abase gather -> 9x int LDS atomics -> scaled writeout =======
__global__ __launch_bounds__(P2_BLK) void vb_phase2(
    const unsigned short* __restrict__ runoff,   // (nblocks, RS)
    const int4*           __restrict__ payload,  // (nblocks, PH1_REC)
    float*                __restrict__ out,      // (A,9), fully overwritten
    int A, int nblocks)
{
    __shared__ unsigned short sst[NROWS_PAD];   // 0.9 KB run start in block
    __shared__ unsigned short roff[NROWS_PAD];  // 0.9 KB excl scan of lens
    __shared__ int   abase[CAPR];               // 16 KB addr base per position
    __shared__ int   sacc[APB * 9];             // 4.5 KB fixed-point acc
    __shared__ int sTotal;                      // ~22.3 KB -> 4 blocks/CU

    // XCD-affinity bin swizzle (T1, bijective): group ~nbin/8 CONSECUTIVE
    // bins per XCD so payload lines shared by adjacent bins' runs are
    // fetched into ONE per-XCD L2 instead of ~3.  (R18: -3.5us)
    int nbin = gridDim.x;
    int q = nbin / NXCD, r0 = nbin % NXCD;
    int xcd = blockIdx.x % NXCD, loc = blockIdx.x / NXCD;
    int b = (xcd < r0 ? xcd * (q + 1) : r0 * (q + 1) + (xcd - r0) * q) + loc;

    int tid = threadIdx.x;

    // run table for this bin: start-in-chunk and length per source block
    for (int r = tid; r < NROWS_PAD; r += P2_BLK) {
        unsigned short s0 = 0, len = 0;
        if (r < nblocks) {
            const unsigned short* row = runoff + (size_t)r * RS + b;
            s0  = row[0];
            len = (unsigned short)(row[1] - row[0]);
        }
        sst[r]  = s0;
        roff[r] = len;   // temporarily lengths; scanned in place below
    }
    for (int i = tid; i < APB * 9; i += P2_BLK) sacc[i] = 0;
    __syncthreads();

    // single-wave exclusive scan over NROWS_PAD rows (7/lane).
    // rows >= nblocks have len 0 so roff[nblocks] == total (sentinel,
    // in-range since nblocks < NROWS_PAD).
    if (tid < 64) {
        int base = tid * 7;
        int pre[7];
        int sum = 0;
        #pragma unroll
        for (int j = 0; j < 7; j++) { pre[j] = sum; sum += roff[base + j]; }
        int incl = sum;
        #pragma unroll
        for (int off = 1; off < 64; off <<= 1) {
            int t = __shfl_up(incl, off, 64);
            if (tid >= off) incl += t;
        }
        int ex = incl - sum;
        #pragma unroll
        for (int j = 0; j < 7; j++)
            roff[base + j] = (unsigned short)(ex + pre[j]);
        if (tid == 63) sTotal = incl;
    }
    __syncthreads();

    int total = sTotal;

    for (int w0 = 0; w0 < total; w0 += CAPR) {       // virtually always 1 pass
        int wend = min(w0 + CAPR, total);
        int nc = wend - w0;

        // abase for this window: disjoint clipped row ranges, no atomics.
        // abase[p-w0] = r*PH1_REC + sst[r] - roff[r]  =>  payload index of
        // global position p is simply p + abase[p-w0].
        for (int r = tid; r < nblocks; r += P2_BLK) {
            int s  = max((int)roff[r], w0);
            int e2 = min((int)roff[r + 1], wend);
            int base_r = r * PH1_REC + (int)sst[r] - (int)roff[r];
            for (int p = s; p < e2; p++)
                abase[p - w0] = base_r;
        }
        __syncthreads();

        // stream records (one dwordx4 each), accumulate via int LDS atomics
        for (int i = tid; i < nc; i += P2_BLK) {
            int4 r = payload[(size_t)(w0 + i + abase[i])];
            int atom = r.x & (APB - 1);
            float2 g01 = unpack2((unsigned)r.y);
            float2 g2t = unpack2((unsigned)r.z);
            float2 t12 = unpack2((unsigned)r.w);
            float g0 = g01.x * ACC_SCALE, g1 = g01.y * ACC_SCALE;
            float g2 = g2t.x * ACC_SCALE;
            float t0 = g2t.y, t1 = t12.x, t2 = t12.y;
            int* s = &sacc[atom * 9];
            atomicAdd(s + 0, __float2int_rn(g0 * t0));
            atomicAdd(s + 1, __float2int_rn(g0 * t1));
            atomicAdd(s + 2, __float2int_rn(g0 * t2));
            atomicAdd(s + 3, __float2int_rn(g1 * t0));
            atomicAdd(s + 4, __float2int_rn(g1 * t1));
            atomicAdd(s + 5, __float2int_rn(g1 * t2));
            atomicAdd(s + 6, __float2int_rn(g2 * t0));
            atomicAdd(s + 7, __float2int_rn(g2 * t1));
            atomicAdd(s + 8, __float2int_rn(g2 * t2));
        }
        __syncthreads();   // abase reused next window (rare)
    }

    // scaled overwrite of out (coalesced)
    size_t gbase = (size_t)b * APB * 9;
    size_t lim = (size_t)A * 9;
    for (int i = tid; i < APB * 9; i += P2_BLK) {
        size_t gi = gbase + i;
        if (gi < lim) out[gi] = (float)sacc[i] * ACC_INV_SCALE;
    }
}

// Fallback: direct per-edge global atomics (correct, slow).
__global__ __launch_bounds__(256) void vb_edge_fallback(
    const float* __restrict__ vecs,
    const int*   __restrict__ centers,
    const int*   __restrict__ neighbors,
    const int*   __restrict__ species,
    const float* __restrict__ W_alch,
    const float* __restrict__ cemb,
    const float* __restrict__ Wc,
    float*       __restrict__ out,
    int E)
{
    __shared__ float sW2[3 * NRAD * 16];
    build_w2(sW2, cemb, Wc, W_alch, threadIdx.x, blockDim.x);
    __syncthreads();

    int e = blockIdx.x * blockDim.x + threadIdx.x;
    if (e >= E) return;
    float vx = vecs[3 * e + 0], vy = vecs[3 * e + 1], vz = vecs[3 * e + 2];
    int c = centers[e];
    int pair = species[c] * 4 + species[neighbors[e]];
    float g[3], t[3];
    if (!edge_math(vx, vy, vz, pair, sW2, g, t)) return;
    float* op = out + (size_t)c * 9;
    #pragma unroll
    for (int m = 0; m < 3; m++)
        #pragma unroll
        for (int o = 0; o < 3; o++)
            atomicAdd(op + m * 3 + o, g[m] * t[o]);
}

extern "C" void kernel_launch(void* const* d_in, const int* in_sizes, int n_in,
                              void* d_out, int out_size, void* d_ws, size_t ws_size,
                              hipStream_t stream) {
    const float* vecs      = (const float*)d_in[0];
    const int*   centers   = (const int*)d_in[1];
    const int*   neighbors = (const int*)d_in[2];
    const int*   species   = (const int*)d_in[3];
    const float* W_alch    = (const float*)d_in[6];
    const float* cemb      = (const float*)d_in[7];
    const float* Wc        = (const float*)d_in[8];
    float*       out       = (float*)d_out;

    int E = in_sizes[1];
    int A = in_sizes[3];
    int nbin    = (A + APB - 1) >> APB_SH;
    int nblocks = (E + PH1_REC - 1) / PH1_REC;

    // ws: [runoff nblocks*RS u16][payload nblocks*4096*16B]
    size_t ro_bytes = ((size_t)nblocks * RS * 2 + 255) & ~(size_t)255;
    size_t need = ro_bytes + (size_t)nblocks * PH1_REC * 16;

    if (nbin + 1 <= RS && nbin <= NBIN_PAD && nblocks < NROWS_PAD &&
        need <= ws_size) {
        unsigned short* runoff = (unsigned short*)d_ws;
        int4* payload = (int4*)((char*)d_ws + ro_bytes);

        vb_phase1<<<nblocks, PH1_BLK, 0, stream>>>(vecs, centers, neighbors,
                                                   species, W_alch, cemb, Wc,
                                                   runoff, payload, E, nbin);
        vb_phase2<<<nbin, P2_BLK, 0, stream>>>(runoff, payload, out, A, nblocks);
    } else {
        hipMemsetAsync(d_out, 0, (size_t)out_size * sizeof(float), stream);
        int grid = (E + 255) / 256;
        vb_edge_fallback<<<grid, 256, 0, stream>>>(vecs, centers, neighbors,
                                                   species, W_alch, cemb, Wc,
                                                   out, E);
    }
}